// Round 1
// baseline (8252.090 us; speedup 1.0000x reference)
//
#include <hip/hip_runtime.h>
#include <cmath>

#define M_TOTAL 4096
#define K_DIM   2048
#define V_DIM   50257
#define BM 128
#define BN 128
#define BK 64
#define VC 1024
#define NCHUNK ((V_DIM + VC - 1) / VC)   /* 50 */
#define MBLK   (M_TOTAL / BM)            /* 32 */
#define LDSPAD 72
#define IGNORE_IDX (-100)
#define Z_REG 1e-4f

typedef __bf16 bf16_t;
typedef bf16_t bf16x8 __attribute__((ext_vector_type(8)));
typedef bf16_t bf16x4 __attribute__((ext_vector_type(4)));
typedef float  f32x4  __attribute__((ext_vector_type(4)));

__device__ inline bf16x4 cvt4(f32x4 v) {
    bf16x4 r;
    r.x = (bf16_t)v.x; r.y = (bf16_t)v.y; r.z = (bf16_t)v.z; r.w = (bf16_t)v.w;
    return r;
}

// Phase A: per (m_block, v_chunk): bf16 MFMA GEMM over K, online softmax over
// the chunk's cols, write per-row (max, sumexp, picked) partials.
__global__ __launch_bounds__(256)
void lce_gemm_stats(const float* __restrict__ X, const float* __restrict__ W,
                    const int* __restrict__ labels,
                    float* __restrict__ pm, float* __restrict__ ps,
                    float* __restrict__ pp)
{
    __shared__ bf16_t As[BM][LDSPAD];
    __shared__ bf16_t Bs[BN][LDSPAD];
    __shared__ float  sm[BM], ss[BM], sp[BM];
    __shared__ float  part_m[2][BM], part_s[2][BM];
    __shared__ int    slab[BM];

    const int bx    = blockIdx.x;
    const int chunk = bx >> 5;      // consecutive blocks share a W chunk (L2/L3 reuse)
    const int mb    = bx & 31;
    const int m0    = mb * BM;
    const int v0    = chunk * VC;
    const int tid   = threadIdx.x;
    const int lane  = tid & 63;
    const int wave  = tid >> 6;
    const int wr    = wave >> 1;    // 2x2 wave grid, each wave 64x64 of the 128x128 tile
    const int wc    = wave & 1;
    const int lo4   = lane & 15;
    const int hi2   = lane >> 4;
    const int sr0   = tid >> 4;     // staging: row group
    const int sc4   = tid & 15;     // staging: float4 col within row

    if (tid < BM) {
        sm[tid] = -INFINITY; ss[tid] = 0.f; sp[tid] = 0.f;
        slab[tid] = labels[m0 + tid];
    }
    __syncthreads();

    const int ncols = min(VC, V_DIM - v0);
    const int nt    = (ncols + 127) >> 7;

    for (int vt = 0; vt < nt; ++vt) {
        f32x4 acc[4][4];
        #pragma unroll
        for (int m = 0; m < 4; ++m)
            #pragma unroll
            for (int n = 0; n < 4; ++n) {
                f32x4 z = {0.f, 0.f, 0.f, 0.f};
                acc[m][n] = z;
            }

        const int vrow0 = v0 + vt * BN;

        for (int kt = 0; kt < K_DIM / BK; ++kt) {
            // ---- stage A (x rows) and B (W rows = vocab cols), fp32 -> bf16 ----
            #pragma unroll
            for (int i = 0; i < 8; ++i) {
                const int row = i * 16 + sr0;
                const f32x4 va = *(const f32x4*)(X + (size_t)(m0 + row) * K_DIM + kt * BK + sc4 * 4);
                *(bf16x4*)&As[row][sc4 * 4] = cvt4(va);
                const int grow = vrow0 + row;
                f32x4 vb = {0.f, 0.f, 0.f, 0.f};
                if (grow < V_DIM)
                    vb = *(const f32x4*)(W + (size_t)grow * K_DIM + kt * BK + sc4 * 4);
                *(bf16x4*)&Bs[row][sc4 * 4] = cvt4(vb);
            }
            __syncthreads();
            // ---- MFMA: 2 k-slices of 32 ----
            #pragma unroll
            for (int ks = 0; ks < 2; ++ks) {
                bf16x8 af[4], bfr[4];
                #pragma unroll
                for (int m = 0; m < 4; ++m)
                    af[m] = *(const bf16x8*)&As[wr * 64 + m * 16 + lo4][ks * 32 + hi2 * 8];
                #pragma unroll
                for (int n = 0; n < 4; ++n)
                    bfr[n] = *(const bf16x8*)&Bs[wc * 64 + n * 16 + lo4][ks * 32 + hi2 * 8];
                #pragma unroll
                for (int m = 0; m < 4; ++m)
                    #pragma unroll
                    for (int n = 0; n < 4; ++n)
                        acc[m][n] = __builtin_amdgcn_mfma_f32_16x16x32_bf16(af[m], bfr[n], acc[m][n], 0, 0, 0);
            }
            __syncthreads();
        }

        // ---- epilogue: per-row max / sumexp over this 128-col tile ----
        // C layout (verified m89): col = lane&15, row = (lane>>4)*4 + reg
        const int vbase = vrow0 + wc * 64;
        #pragma unroll
        for (int m = 0; m < 4; ++m) {
            #pragma unroll
            for (int j = 0; j < 4; ++j) {
                const int rloc = wr * 64 + m * 16 + hi2 * 4 + j;
                const int lbl  = slab[rloc];
                float vmax = -INFINITY;
                float v_[4];
                #pragma unroll
                for (int n = 0; n < 4; ++n) {
                    const int gcol = vbase + n * 16 + lo4;
                    const float v  = acc[m][n][j];
                    const bool ok  = (gcol < V_DIM);
                    v_[n] = ok ? v : -INFINITY;
                    if (ok && gcol == lbl) sp[rloc] = v;   // one writer per row per chunk
                    vmax = fmaxf(vmax, v_[n]);
                }
                #pragma unroll
                for (int d = 1; d < 16; d <<= 1)
                    vmax = fmaxf(vmax, __shfl_xor(vmax, d, 64));
                float s = 0.f;
                #pragma unroll
                for (int n = 0; n < 4; ++n)
                    s += __expf(v_[n] - vmax);   // exp(-inf)=0 for masked
                #pragma unroll
                for (int d = 1; d < 16; d <<= 1)
                    s += __shfl_xor(s, d, 64);
                if (lo4 == 0) {
                    part_m[wc][rloc] = vmax;
                    part_s[wc][rloc] = s;
                }
            }
        }
        __syncthreads();
        // ---- combine the two col-half waves with the running state ----
        if (tid < BM) {
            const float om  = sm[tid], os = ss[tid];
            const float m0_ = part_m[0][tid], s0 = part_s[0][tid];
            const float m1_ = part_m[1][tid], s1 = part_s[1][tid];
            const float nm  = fmaxf(om, fmaxf(m0_, m1_));
            float ns = 0.f;
            if (om  > -INFINITY) ns += os * __expf(om  - nm);
            if (m0_ > -INFINITY) ns += s0 * __expf(m0_ - nm);
            if (m1_ > -INFINITY) ns += s1 * __expf(m1_ - nm);
            sm[tid] = nm; ss[tid] = ns;
        }
        // no barrier needed here: next epilogue's part_* writes are separated
        // by the K-loop barriers; combine threads reach the staging barrier.
    }

    if (tid < BM) {
        const size_t idx = (size_t)chunk * M_TOTAL + (m0 + tid);
        pm[idx] = sm[tid];
        ps[idx] = ss[tid];
        pp[idx] = sp[tid];
    }
}

// Phase B1: combine chunk partials per row -> nll, lse^2; block partial sums.
__global__ __launch_bounds__(256)
void lce_row_reduce(const float* __restrict__ pm, const float* __restrict__ ps,
                    const float* __restrict__ pp, const int* __restrict__ labels,
                    float* __restrict__ pb)
{
    const int r   = blockIdx.x * 256 + threadIdx.x;
    const int lbl = labels[r];
    float nll = 0.f, zsq = 0.f, val = 0.f;
    if (lbl != IGNORE_IDX) {
        float M = -INFINITY;
        for (int c = 0; c < NCHUNK; ++c)
            M = fmaxf(M, pm[(size_t)c * M_TOTAL + r]);
        float S = 0.f, P = 0.f;
        for (int c = 0; c < NCHUNK; ++c) {
            const float mc = pm[(size_t)c * M_TOTAL + r];
            if (mc > -INFINITY) S += ps[(size_t)c * M_TOTAL + r] * expf(mc - M);
            P += pp[(size_t)c * M_TOTAL + r];
        }
        const float lse = M + logf(S);
        nll = lse - P;
        zsq = lse * lse;
        val = 1.f;
    }
    #pragma unroll
    for (int d = 32; d; d >>= 1) {
        nll += __shfl_down(nll, d, 64);
        zsq += __shfl_down(zsq, d, 64);
        val += __shfl_down(val, d, 64);
    }
    __shared__ float red[3][4];
    const int wv = threadIdx.x >> 6, ln = threadIdx.x & 63;
    if (ln == 0) { red[0][wv] = nll; red[1][wv] = zsq; red[2][wv] = val; }
    __syncthreads();
    if (threadIdx.x == 0) {
        float a = 0.f, b = 0.f, c_ = 0.f;
        #pragma unroll
        for (int i = 0; i < 4; ++i) { a += red[0][i]; b += red[1][i]; c_ += red[2][i]; }
        pb[blockIdx.x * 3 + 0] = a;
        pb[blockIdx.x * 3 + 1] = b;
        pb[blockIdx.x * 3 + 2] = c_;
    }
}

// Phase B2: final scalar.
__global__ void lce_finalize(const float* __restrict__ pb, float* __restrict__ out)
{
    float a = 0.f, b = 0.f, c_ = 0.f;
    for (int i = 0; i < MBLK / 2; ++i) {   // 16 blocks in B1
        a  += pb[i * 3 + 0];
        b  += pb[i * 3 + 1];
        c_ += pb[i * 3 + 2];
    }
    const float denom = fmaxf(c_, 1.f);
    float loss = a / denom;
    if (c_ > 0.f) loss += Z_REG * (b / denom);
    out[0] = loss;
}

extern "C" void kernel_launch(void* const* d_in, const int* in_sizes, int n_in,
                              void* d_out, int out_size, void* d_ws, size_t ws_size,
                              hipStream_t stream)
{
    const float* x      = (const float*)d_in[0];
    const int*   labels = (const int*)d_in[1];
    const float* w      = (const float*)d_in[2];
    float*       out    = (float*)d_out;

    float* pm = (float*)d_ws;                       // [NCHUNK][4096]
    float* ps = pm + (size_t)NCHUNK * M_TOTAL;      // [NCHUNK][4096]
    float* pp = ps + (size_t)NCHUNK * M_TOTAL;      // [NCHUNK][4096]
    float* pb = pp + (size_t)NCHUNK * M_TOTAL;      // [16][3]

    lce_gemm_stats<<<dim3(NCHUNK * MBLK), dim3(256), 0, stream>>>(x, w, labels, pm, ps, pp);
    lce_row_reduce<<<dim3(16), dim3(256), 0, stream>>>(pm, ps, pp, labels, pb);
    lce_finalize<<<dim3(1), dim3(1), 0, stream>>>(pb, out);
}

// Round 2
// 1367.246 us; speedup vs baseline: 6.0356x; 6.0356x over previous
//
#include <hip/hip_runtime.h>
#include <cmath>
#include <cstdint>

#define M_TOTAL 4096
#define K_DIM   2048
#define V_DIM   50257
#define V_PAD   50304            /* 393*128, zero-padded rows in converted W */
#define BM 128
#define BK 64
#define VC 1024
#define NCHUNK 50                /* ceil(50257/1024) */
#define MBLK 32                  /* 4096/128 */
#define NKT (K_DIM / BK)         /* 32 */
#define IGNORE_IDX (-100)
#define Z_REG 1e-4f

typedef __bf16 bf16_t;
typedef bf16_t bf16x8 __attribute__((ext_vector_type(8)));
typedef bf16_t bf16x4 __attribute__((ext_vector_type(4)));
typedef float  f32x4  __attribute__((ext_vector_type(4)));

typedef const __attribute__((address_space(1))) void g_cvoid;
typedef __attribute__((address_space(3))) void l_void;

// async global->LDS, 16B per lane; LDS dest = wave-uniform base + lane*16
__device__ __forceinline__ void gll16(const void* g, void* l) {
    __builtin_amdgcn_global_load_lds((g_cvoid*)(uintptr_t)g,
                                     (l_void*)(uint32_t)(uintptr_t)l, 16, 0, 0);
}

__device__ inline bf16x4 cvt4(f32x4 v) {
    bf16x4 r;
    r.x = (bf16_t)v.x; r.y = (bf16_t)v.y; r.z = (bf16_t)v.z; r.w = (bf16_t)v.w;
    return r;
}

// ---------------- fp32 -> bf16 convert (pads rows >= valid8 with zeros) ----
__global__ __launch_bounds__(256)
void cvt_f32_bf16(const float* __restrict__ src, bf16_t* __restrict__ dst,
                  long long total8, long long valid8)
{
    const long long stride = (long long)gridDim.x * 256;
    for (long long i = (long long)blockIdx.x * 256 + threadIdx.x; i < total8; i += stride) {
        bf16x8 o;
        if (i < valid8) {
            const float* s = src + i * 8;
            const f32x4 a = *(const f32x4*)s;
            const f32x4 b = *(const f32x4*)(s + 4);
            o[0]=(bf16_t)a.x; o[1]=(bf16_t)a.y; o[2]=(bf16_t)a.z; o[3]=(bf16_t)a.w;
            o[4]=(bf16_t)b.x; o[5]=(bf16_t)b.y; o[6]=(bf16_t)b.z; o[7]=(bf16_t)b.w;
        } else {
            #pragma unroll
            for (int z = 0; z < 8; ++z) o[z] = (bf16_t)0.f;
        }
        *(bf16x8*)(dst + i * 8) = o;
    }
}

// ---------------- main fused GEMM + online softmax stats -------------------
// bf16 inputs, global_load_lds staging, double-buffered LDS, 1 barrier/kt,
// XOR-swizzled LDS layout (swizzle pre-applied on global source addresses).
__global__ __launch_bounds__(256, 2)
void lce_gemm_bf16(const bf16_t* __restrict__ Xb, const bf16_t* __restrict__ Wb,
                   const int* __restrict__ labels,
                   float* __restrict__ pm, float* __restrict__ ps,
                   float* __restrict__ pp)
{
    __shared__ bf16_t As[2][BM * BK];   // 2 x 16KB
    __shared__ bf16_t Bs[2][BM * BK];   // 2 x 16KB  (total exactly 64KB)

    const int bid   = blockIdx.x;
    const int wg    = (bid & 7) * (NCHUNK * MBLK / 8) + (bid >> 3); // XCD swizzle (1600%8==0)
    const int chunk = wg >> 5;
    const int mb    = wg & 31;
    const int m0    = mb * BM;
    const int v0    = chunk * VC;

    const int tid  = threadIdx.x;
    const int lane = tid & 63;
    const int wave = tid >> 6;
    const int wr   = wave >> 1;      // 2x2 wave grid over the 128x128 tile
    const int wc   = wave & 1;
    const int lo4  = lane & 15;
    const int hi2  = lane >> 4;
    const int sw   = (lo4 & 7) << 4; // read-side XOR (byte units)

    // staging geometry: issue q of wave w covers LDS rows w*32+q*8 .. +7,
    // lane l -> row w*32+q*8+(l>>3), swizzled col element ((l&7)^(l>>3))*8
    const int srow = wave * 32 + (lane >> 3);
    const int scol = ((lane & 7) ^ (lane >> 3)) * 8;
    const bf16_t* baseA = Xb + (size_t)(m0 + srow) * K_DIM + scol;

    // init picked-logit slot for this block's rows (one writer later)
    if (tid < BM) pp[(size_t)chunk * M_TOTAL + m0 + tid] = 0.f;

    // labels for the 16 rows this thread reduces
    int lbl[4][4];
    #pragma unroll
    for (int m = 0; m < 4; ++m)
        #pragma unroll
        for (int j = 0; j < 4; ++j)
            lbl[m][j] = labels[m0 + wr * 64 + m * 16 + hi2 * 4 + j];

    float run_m[4][4], run_s[4][4];
    #pragma unroll
    for (int m = 0; m < 4; ++m)
        #pragma unroll
        for (int j = 0; j < 4; ++j) { run_m[m][j] = -INFINITY; run_s[m][j] = 0.f; }

    const int ncols = (V_DIM - v0 < VC) ? (V_DIM - v0) : VC;
    const int nt    = (ncols + 127) >> 7;

#define STAGE(buf, ktv) do {                                             \
        const bf16_t* _sa = baseA + (ktv) * BK;                          \
        const bf16_t* _sb = baseB + (ktv) * BK;                          \
        char* _da = (char*)&As[buf][0] + wave * 4096;                    \
        char* _db = (char*)&Bs[buf][0] + wave * 4096;                    \
        _Pragma("unroll")                                                \
        for (int q = 0; q < 4; ++q) {                                    \
            gll16(_sa + q * (8 * K_DIM), _da + q * 1024);                \
            gll16(_sb + q * (8 * K_DIM), _db + q * 1024);                \
        }                                                                \
    } while (0)

    for (int vt = 0; vt < nt; ++vt) {
        const int vrow0 = v0 + vt * BM;
        const bf16_t* baseB = Wb + (size_t)(vrow0 + srow) * K_DIM + scol;

        f32x4 acc[4][4];
        #pragma unroll
        for (int m = 0; m < 4; ++m)
            #pragma unroll
            for (int n = 0; n < 4; ++n) {
                f32x4 z = {0.f, 0.f, 0.f, 0.f};
                acc[m][n] = z;
            }

        int cur = 0;
        STAGE(0, 0);
        __syncthreads();                       // drain prologue loads

        for (int kt = 0; kt < NKT; ++kt) {
            if (kt + 1 < NKT) STAGE(cur ^ 1, kt + 1);   // prefetch flies under MFMA
            const char* Ab = (const char*)&As[cur][0];
            const char* Bb = (const char*)&Bs[cur][0];
            #pragma unroll
            for (int ks = 0; ks < 2; ++ks) {
                const int cbs = (ks * 64 + hi2 * 16) ^ sw;
                bf16x8 af[4], bv[4];
                #pragma unroll
                for (int m = 0; m < 4; ++m)
                    af[m] = *(const bf16x8*)(Ab + (wr * 64 + m * 16 + lo4) * 128 + cbs);
                #pragma unroll
                for (int n = 0; n < 4; ++n)
                    bv[n] = *(const bf16x8*)(Bb + (wc * 64 + n * 16 + lo4) * 128 + cbs);
                #pragma unroll
                for (int m = 0; m < 4; ++m)
                    #pragma unroll
                    for (int n = 0; n < 4; ++n)
                        acc[m][n] = __builtin_amdgcn_mfma_f32_16x16x32_bf16(
                            af[m], bv[n], acc[m][n], 0, 0, 0);
            }
            __syncthreads();                   // one barrier per kt (drains prefetch)
            cur ^= 1;
        }

        // epilogue: per-row max/sumexp over this 128-col tile, all in registers.
        // C layout (m89): col = lane&15, row = (lane>>4)*4 + reg
        #pragma unroll
        for (int m = 0; m < 4; ++m) {
            #pragma unroll
            for (int j = 0; j < 4; ++j) {
                float v_[4];
                float vmax = -INFINITY;
                #pragma unroll
                for (int n = 0; n < 4; ++n) {
                    const int gcol = vrow0 + wc * 64 + n * 16 + lo4;
                    const float v  = acc[m][n][j];
                    const bool ok  = (gcol < V_DIM);
                    v_[n] = ok ? v : -INFINITY;
                    if (ok && gcol == lbl[m][j])
                        pp[(size_t)chunk * M_TOTAL + m0 + wr * 64 + m * 16 + hi2 * 4 + j] = v;
                    vmax = fmaxf(vmax, v_[n]);
                }
                #pragma unroll
                for (int d = 1; d < 16; d <<= 1)
                    vmax = fmaxf(vmax, __shfl_xor(vmax, d, 64));
                if (vmax > -INFINITY) {        // uniform within 16-lane group
                    float s = 0.f;
                    #pragma unroll
                    for (int n = 0; n < 4; ++n) s += __expf(v_[n] - vmax);
                    #pragma unroll
                    for (int d = 1; d < 16; d <<= 1)
                        s += __shfl_xor(s, d, 64);
                    const float nm = fmaxf(run_m[m][j], vmax);
                    run_s[m][j] = run_s[m][j] * __expf(run_m[m][j] - nm)
                                + s * __expf(vmax - nm);
                    run_m[m][j] = nm;
                }
            }
        }
    }
#undef STAGE

    // merge the two column-half waves via LDS scratch (reuse As)
    float* scr = (float*)&As[0][0];    // 512 floats
    if (lo4 == 0) {
        #pragma unroll
        for (int m = 0; m < 4; ++m)
            #pragma unroll
            for (int j = 0; j < 4; ++j) {
                const int row = wr * 64 + m * 16 + hi2 * 4 + j;
                scr[wc * 128 + row]       = run_m[m][j];
                scr[256 + wc * 128 + row] = run_s[m][j];
            }
    }
    __syncthreads();
    if (tid < BM) {
        const float ma  = scr[tid],       mb_ = scr[128 + tid];
        const float sa  = scr[256 + tid], sb  = scr[384 + tid];
        const float nm  = fmaxf(ma, mb_);
        float ns = 0.f;
        if (ma  > -INFINITY) ns += sa * __expf(ma  - nm);
        if (mb_ > -INFINITY) ns += sb * __expf(mb_ - nm);
        const size_t idx = (size_t)chunk * M_TOTAL + m0 + tid;
        pm[idx] = nm;
        ps[idx] = ns;
    }
}

// ---------------- fallback fused path (round-0 kernel, needs tiny ws) ------
#define LDSPAD 72
__global__ __launch_bounds__(256)
void lce_gemm_stats_fused(const float* __restrict__ X, const float* __restrict__ W,
                          const int* __restrict__ labels,
                          float* __restrict__ pm, float* __restrict__ ps,
                          float* __restrict__ pp)
{
    __shared__ bf16_t As[BM][LDSPAD];
    __shared__ bf16_t Bsh[BM][LDSPAD];
    __shared__ float  sm[BM], ss[BM], sp[BM];
    __shared__ float  part_m[2][BM], part_s[2][BM];
    __shared__ int    slab[BM];

    const int bx    = blockIdx.x;
    const int chunk = bx >> 5;
    const int mb    = bx & 31;
    const int m0    = mb * BM;
    const int v0    = chunk * VC;
    const int tid   = threadIdx.x;
    const int lane  = tid & 63;
    const int wave  = tid >> 6;
    const int wr    = wave >> 1;
    const int wc    = wave & 1;
    const int lo4   = lane & 15;
    const int hi2   = lane >> 4;
    const int sr0   = tid >> 4;
    const int sc4   = tid & 15;

    if (tid < BM) {
        sm[tid] = -INFINITY; ss[tid] = 0.f; sp[tid] = 0.f;
        slab[tid] = labels[m0 + tid];
    }
    __syncthreads();

    const int ncols = min(VC, V_DIM - v0);
    const int nt    = (ncols + 127) >> 7;

    for (int vt = 0; vt < nt; ++vt) {
        f32x4 acc[4][4];
        #pragma unroll
        for (int m = 0; m < 4; ++m)
            #pragma unroll
            for (int n = 0; n < 4; ++n) {
                f32x4 z = {0.f, 0.f, 0.f, 0.f};
                acc[m][n] = z;
            }
        const int vrow0 = v0 + vt * BM;
        for (int kt = 0; kt < NKT; ++kt) {
            #pragma unroll
            for (int i = 0; i < 8; ++i) {
                const int row = i * 16 + sr0;
                const f32x4 va = *(const f32x4*)(X + (size_t)(m0 + row) * K_DIM + kt * BK + sc4 * 4);
                *(bf16x4*)&As[row][sc4 * 4] = cvt4(va);
                const int grow = vrow0 + row;
                f32x4 vb = {0.f, 0.f, 0.f, 0.f};
                if (grow < V_DIM)
                    vb = *(const f32x4*)(W + (size_t)grow * K_DIM + kt * BK + sc4 * 4);
                *(bf16x4*)&Bsh[row][sc4 * 4] = cvt4(vb);
            }
            __syncthreads();
            #pragma unroll
            for (int ks = 0; ks < 2; ++ks) {
                bf16x8 af[4], bfr[4];
                #pragma unroll
                for (int m = 0; m < 4; ++m)
                    af[m] = *(const bf16x8*)&As[wr * 64 + m * 16 + lo4][ks * 32 + hi2 * 8];
                #pragma unroll
                for (int n = 0; n < 4; ++n)
                    bfr[n] = *(const bf16x8*)&Bsh[wc * 64 + n * 16 + lo4][ks * 32 + hi2 * 8];
                #pragma unroll
                for (int m = 0; m < 4; ++m)
                    #pragma unroll
                    for (int n = 0; n < 4; ++n)
                        acc[m][n] = __builtin_amdgcn_mfma_f32_16x16x32_bf16(af[m], bfr[n], acc[m][n], 0, 0, 0);
            }
            __syncthreads();
        }
        const int vbase = vrow0 + wc * 64;
        #pragma unroll
        for (int m = 0; m < 4; ++m) {
            #pragma unroll
            for (int j = 0; j < 4; ++j) {
                const int rloc = wr * 64 + m * 16 + hi2 * 4 + j;
                const int lb   = slab[rloc];
                float vmax = -INFINITY;
                float v_[4];
                #pragma unroll
                for (int n = 0; n < 4; ++n) {
                    const int gcol = vbase + n * 16 + lo4;
                    const float v  = acc[m][n][j];
                    const bool ok  = (gcol < V_DIM);
                    v_[n] = ok ? v : -INFINITY;
                    if (ok && gcol == lb) sp[rloc] = v;
                    vmax = fmaxf(vmax, v_[n]);
                }
                #pragma unroll
                for (int d = 1; d < 16; d <<= 1)
                    vmax = fmaxf(vmax, __shfl_xor(vmax, d, 64));
                float s = 0.f;
                #pragma unroll
                for (int n = 0; n < 4; ++n) s += __expf(v_[n] - vmax);
                #pragma unroll
                for (int d = 1; d < 16; d <<= 1) s += __shfl_xor(s, d, 64);
                if (lo4 == 0) { part_m[wc][rloc] = vmax; part_s[wc][rloc] = s; }
            }
        }
        __syncthreads();
        if (tid < BM) {
            const float om  = sm[tid], os = ss[tid];
            const float m0_ = part_m[0][tid], s0 = part_s[0][tid];
            const float m1_ = part_m[1][tid], s1 = part_s[1][tid];
            const float nm  = fmaxf(om, fmaxf(m0_, m1_));
            float ns = 0.f;
            if (om  > -INFINITY) ns += os * __expf(om  - nm);
            if (m0_ > -INFINITY) ns += s0 * __expf(m0_ - nm);
            if (m1_ > -INFINITY) ns += s1 * __expf(m1_ - nm);
            sm[tid] = nm; ss[tid] = ns;
        }
    }
    __syncthreads();
    if (tid < BM) {
        const size_t idx = (size_t)chunk * M_TOTAL + (m0 + tid);
        pm[idx] = sm[tid]; ps[idx] = ss[tid]; pp[idx] = sp[tid];
    }
}

// ---------------- chunk-combine + finalize ---------------------------------
__global__ __launch_bounds__(256)
void lce_row_reduce(const float* __restrict__ pm, const float* __restrict__ ps,
                    const float* __restrict__ pp, const int* __restrict__ labels,
                    float* __restrict__ pb)
{
    const int r   = blockIdx.x * 256 + threadIdx.x;
    const int lbl = labels[r];
    float nll = 0.f, zsq = 0.f, val = 0.f;
    if (lbl != IGNORE_IDX) {
        float M = -INFINITY;
        for (int c = 0; c < NCHUNK; ++c)
            M = fmaxf(M, pm[(size_t)c * M_TOTAL + r]);
        float S = 0.f, P = 0.f;
        for (int c = 0; c < NCHUNK; ++c) {
            const float mc = pm[(size_t)c * M_TOTAL + r];
            if (mc > -INFINITY) S += ps[(size_t)c * M_TOTAL + r] * expf(mc - M);
            P += pp[(size_t)c * M_TOTAL + r];
        }
        const float lse = M + logf(S);
        nll = lse - P;
        zsq = lse * lse;
        val = 1.f;
    }
    #pragma unroll
    for (int d = 32; d; d >>= 1) {
        nll += __shfl_down(nll, d, 64);
        zsq += __shfl_down(zsq, d, 64);
        val += __shfl_down(val, d, 64);
    }
    __shared__ float red[3][4];
    const int wv = threadIdx.x >> 6, ln = threadIdx.x & 63;
    if (ln == 0) { red[0][wv] = nll; red[1][wv] = zsq; red[2][wv] = val; }
    __syncthreads();
    if (threadIdx.x == 0) {
        float a = 0.f, b = 0.f, c_ = 0.f;
        #pragma unroll
        for (int i = 0; i < 4; ++i) { a += red[0][i]; b += red[1][i]; c_ += red[2][i]; }
        pb[blockIdx.x * 3 + 0] = a;
        pb[blockIdx.x * 3 + 1] = b;
        pb[blockIdx.x * 3 + 2] = c_;
    }
}

__global__ void lce_finalize(const float* __restrict__ pb, float* __restrict__ out)
{
    float a = 0.f, b = 0.f, c_ = 0.f;
    for (int i = 0; i < 16; ++i) {
        a  += pb[i * 3 + 0];
        b  += pb[i * 3 + 1];
        c_ += pb[i * 3 + 2];
    }
    const float denom = fmaxf(c_, 1.f);
    float loss = a / denom;
    if (c_ > 0.f) loss += Z_REG * (b / denom);
    out[0] = loss;
}

extern "C" void kernel_launch(void* const* d_in, const int* in_sizes, int n_in,
                              void* d_out, int out_size, void* d_ws, size_t ws_size,
                              hipStream_t stream)
{
    const float* x      = (const float*)d_in[0];
    const int*   labels = (const int*)d_in[1];
    const float* w      = (const float*)d_in[2];
    float*       out    = (float*)d_out;

    const size_t wb_elems = (size_t)V_PAD * K_DIM;      // 103,022,592
    const size_t xb_elems = (size_t)M_TOTAL * K_DIM;    // 8,388,608
    const size_t stat_n   = (size_t)NCHUNK * M_TOTAL;   // 204,800
    const size_t stat_off = wb_elems * 2 + xb_elems * 2;
    const size_t need     = stat_off + stat_n * 3 * sizeof(float) + 256;

    if (ws_size >= need) {
        bf16_t* Wb = (bf16_t*)d_ws;
        bf16_t* Xb = Wb + wb_elems;
        float*  pm = (float*)((char*)d_ws + stat_off);
        float*  ps = pm + stat_n;
        float*  pp = ps + stat_n;
        float*  pb = pp + stat_n;

        cvt_f32_bf16<<<dim3(4096), dim3(256), 0, stream>>>(
            w, Wb, (long long)(wb_elems / 8), (long long)((size_t)V_DIM * K_DIM / 8));
        cvt_f32_bf16<<<dim3(1024), dim3(256), 0, stream>>>(
            x, Xb, (long long)(xb_elems / 8), (long long)(xb_elems / 8));
        lce_gemm_bf16<<<dim3(NCHUNK * MBLK), dim3(256), 0, stream>>>(
            Xb, Wb, labels, pm, ps, pp);
        lce_row_reduce<<<dim3(16), dim3(256), 0, stream>>>(pm, ps, pp, labels, pb);
        lce_finalize<<<dim3(1), dim3(1), 0, stream>>>(pb, out);
    } else {
        float* pm = (float*)d_ws;
        float* ps = pm + stat_n;
        float* pp = ps + stat_n;
        float* pb = pp + stat_n;
        lce_gemm_stats_fused<<<dim3(NCHUNK * MBLK), dim3(256), 0, stream>>>(
            x, w, labels, pm, ps, pp);
        lce_row_reduce<<<dim3(16), dim3(256), 0, stream>>>(pm, ps, pp, labels, pb);
        lce_finalize<<<dim3(1), dim3(1), 0, stream>>>(pb, out);
    }
}

// Round 3
// 1130.496 us; speedup vs baseline: 7.2995x; 1.2094x over previous
//
#include <hip/hip_runtime.h>
#include <cmath>
#include <cstdint>

#define M_TOTAL 4096
#define K_DIM   2048
#define V_DIM   50257
#define V_PAD   50432            /* 197*256, zero-padded rows in converted W */
#define NVB     197              /* vocab blocks of 256 */
#define BM 256
#define BK 32
#define NKT (K_DIM / BK)         /* 64 */
#define IGNORE_IDX (-100)
#define Z_REG 1e-4f

typedef __bf16 bf16_t;
typedef bf16_t bf16x8 __attribute__((ext_vector_type(8)));
typedef bf16_t bf16x4 __attribute__((ext_vector_type(4)));
typedef float  f32x4  __attribute__((ext_vector_type(4)));

typedef const __attribute__((address_space(1))) void g_cvoid;
typedef __attribute__((address_space(3))) void l_void;

// async global->LDS, 16B per lane; LDS dest = wave-uniform base + lane*16
__device__ __forceinline__ void gll16(const void* g, void* l) {
    __builtin_amdgcn_global_load_lds((g_cvoid*)(uintptr_t)g,
                                     (l_void*)(uint32_t)(uintptr_t)l, 16, 0, 0);
}

__device__ inline bf16x4 cvt4(f32x4 v) {
    bf16x4 r;
    r.x = (bf16_t)v.x; r.y = (bf16_t)v.y; r.z = (bf16_t)v.z; r.w = (bf16_t)v.w;
    return r;
}

// ---------------- fp32 -> bf16 convert (pads rows >= valid8 with zeros) ----
__global__ __launch_bounds__(256)
void cvt_f32_bf16(const float* __restrict__ src, bf16_t* __restrict__ dst,
                  long long total8, long long valid8)
{
    const long long stride = (long long)gridDim.x * 256;
    for (long long i = (long long)blockIdx.x * 256 + threadIdx.x; i < total8; i += stride) {
        bf16x8 o;
        if (i < valid8) {
            const float* s = src + i * 8;
            const f32x4 a = *(const f32x4*)s;
            const f32x4 b = *(const f32x4*)(s + 4);
            o[0]=(bf16_t)a.x; o[1]=(bf16_t)a.y; o[2]=(bf16_t)a.z; o[3]=(bf16_t)a.w;
            o[4]=(bf16_t)b.x; o[5]=(bf16_t)b.y; o[6]=(bf16_t)b.z; o[7]=(bf16_t)b.w;
        } else {
            #pragma unroll
            for (int z = 0; z < 8; ++z) o[z] = (bf16_t)0.f;
        }
        *(bf16x8*)(dst + i * 8) = o;
    }
}

// ---------------- 8-phase-style fused GEMM + online softmax stats ----------
// 256x256 tile, BK=32, ring-4 LDS slots (lead-3 prefetch), counted vmcnt,
// setprio around MFMA clusters, row-pair XOR LDS swizzle (2-way max).
__global__ __launch_bounds__(512, 2)
void lce_gemm8(const bf16_t* __restrict__ Xb, const bf16_t* __restrict__ Wb,
               float* __restrict__ pm, float* __restrict__ ps)
{
    __shared__ __align__(16) bf16_t As[4][BM * BK];   // 4 x 16KB
    __shared__ __align__(16) bf16_t Bs[4][BM * BK];   // 4 x 16KB  (128KB total)

    const int bid = blockIdx.x;
    // XCD swizzle (3152 = 8*394, bijective); m-inner so one W panel's 16
    // consumers are temporally adjacent (W HBM-read ~once, L2/L3 serve rest)
    const int wg = (bid & 7) * (NVB * 16 / 8) + (bid >> 3);
    const int vb = wg >> 4;
    const int mb = wg & 15;
    const int m0 = mb * BM;
    const int v0 = vb * BM;

    const int tid  = threadIdx.x;
    const int lane = tid & 63;
    const int wave = tid >> 6;
    const int wr   = wave >> 2;     // 2x4 wave grid: per-wave 128 rows x 64 cols
    const int wc   = wave & 3;
    const int lo4  = lane & 15;
    const int hi2  = lane >> 4;

    // ---- read-side swizzled LDS offset (constant per thread) ----
    // layout: row r, elem-group g (8 bf16) at byte (r>>1)*128 + s*16,
    //   s = (((r&1)<<2)|g) ^ ((r>>1)&7).  For frag reads r = rbase+lo4,
    //   rbase % 16 == 0, g = hi2:
    const int ldsoff = ((lo4 >> 1) << 7)
                     | (((((lo4 & 1) << 2) | hi2) ^ ((lo4 >> 1) & 7)) << 4);

    // ---- staging geometry (inverse swizzle folded into global address) ----
    // lane l writes LDS linear byte wave*1024 + l*16 = (R=l>>3, s_lin=l&7);
    // must hold global (row 2*(l>>3)+(s0>>2), group s0&3), s0 = (l&7)^(l>>3)
    const int l7   = lane & 7, l3 = lane >> 3;
    const int s0   = l7 ^ l3;
    const int srow = (wave << 4) + (l3 << 1) + (s0 >> 2);  // row within 128-row unit
    const int scol = (s0 & 3) << 3;                        // bf16 element offset
    const bf16_t* baseA = Xb + (size_t)(m0 + srow) * K_DIM + scol;
    const bf16_t* baseB = Wb + (size_t)(v0 + srow) * K_DIM + scol;
    char* ldsA_w = (char*)&As[0][0] + wave * 1024;
    char* ldsB_w = (char*)&Bs[0][0] + wave * 1024;
    const size_t U1 = (size_t)128 * K_DIM;   // unit-1 row offset

    f32x4 acc[8][4];
    #pragma unroll
    for (int m = 0; m < 8; ++m)
        #pragma unroll
        for (int n = 0; n < 4; ++n) {
            f32x4 z = {0.f, 0.f, 0.f, 0.f};
            acc[m][n] = z;
        }

    // ---- prologue: stage tiles 0,1,2; wait tile 0 (8 issues may remain) ----
    #pragma unroll
    for (int tt = 0; tt < 3; ++tt) {
        gll16(baseA + (size_t)tt * BK,      ldsA_w + tt * 16384);
        gll16(baseA + (size_t)tt * BK + U1, ldsA_w + tt * 16384 + 8192);
        gll16(baseB + (size_t)tt * BK,      ldsB_w + tt * 16384);
        gll16(baseB + (size_t)tt * BK + U1, ldsB_w + tt * 16384 + 8192);
    }
    asm volatile("s_waitcnt vmcnt(8)" ::: "memory");
    __builtin_amdgcn_s_barrier();

    const char* AbBase = (const char*)&As[0][0];
    const char* BbBase = (const char*)&Bs[0][0];

    for (int t = 0; t < NKT; ++t) {
        const int  slot = t & 3;
        const char* Ab = AbBase + slot * 16384;
        const char* Bb = BbBase + slot * 16384;
        const int  tn  = t + 3;
        const bool st  = tn < NKT;
        const int  sn  = tn & 3;

        // ================= phase 0 =================
        bf16x8 bv[4], af[4];
        #pragma unroll
        for (int n = 0; n < 4; ++n)
            bv[n] = *(const bf16x8*)(Bb + (wc * 64 + n * 16) * 64 + ldsoff);
        #pragma unroll
        for (int m = 0; m < 4; ++m)
            af[m] = *(const bf16x8*)(Ab + (wr * 128 + m * 16) * 64 + ldsoff);
        if (st) {
            gll16(baseA + (size_t)tn * BK,      ldsA_w + sn * 16384);
            gll16(baseA + (size_t)tn * BK + U1, ldsA_w + sn * 16384 + 8192);
        }
        __builtin_amdgcn_s_barrier();
        asm volatile("s_waitcnt lgkmcnt(0)" ::: "memory");
        __builtin_amdgcn_s_setprio(1);
        #pragma unroll
        for (int m = 0; m < 4; ++m)
            #pragma unroll
            for (int n = 0; n < 4; ++n)
                acc[m][n] = __builtin_amdgcn_mfma_f32_16x16x32_bf16(
                    af[m], bv[n], acc[m][n], 0, 0, 0);
        __builtin_amdgcn_s_setprio(0);
        __builtin_amdgcn_s_barrier();

        // ================= phase 1 =================
        #pragma unroll
        for (int m = 0; m < 4; ++m)
            af[m] = *(const bf16x8*)(Ab + (wr * 128 + 64 + m * 16) * 64 + ldsoff);
        if (st) {
            gll16(baseB + (size_t)tn * BK,      ldsB_w + sn * 16384);
            gll16(baseB + (size_t)tn * BK + U1, ldsB_w + sn * 16384 + 8192);
        }
        __builtin_amdgcn_s_barrier();
        asm volatile("s_waitcnt lgkmcnt(0)" ::: "memory");
        __builtin_amdgcn_s_setprio(1);
        #pragma unroll
        for (int m = 0; m < 4; ++m)
            #pragma unroll
            for (int n = 0; n < 4; ++n)
                acc[4 + m][n] = __builtin_amdgcn_mfma_f32_16x16x32_bf16(
                    af[m], bv[n], acc[4 + m][n], 0, 0, 0);
        __builtin_amdgcn_s_setprio(0);
        // ---- K-tile boundary: counted vmcnt, never full drain mid-loop ----
        if (t < NKT - 3)      asm volatile("s_waitcnt vmcnt(8)" ::: "memory");
        else if (t == NKT - 3) asm volatile("s_waitcnt vmcnt(4)" ::: "memory");
        else if (t == NKT - 2) asm volatile("s_waitcnt vmcnt(0)" ::: "memory");
        __builtin_amdgcn_s_barrier();
    }

    // ---- epilogue: per-row max/sumexp over this block's 256 cols ----------
    // C layout (m89): col = lane&15, row = (lane>>4)*4 + reg
    float* scrM = (float*)&As[0][0];        // [256][4] wc-partials (4KB)
    float* scrS = scrM + 1024;              // [256][4] (4KB) — slot 0 reuse
    #pragma unroll
    for (int m = 0; m < 8; ++m) {
        #pragma unroll
        for (int j = 0; j < 4; ++j) {
            float v_[4];
            float vmax = -INFINITY;
            #pragma unroll
            for (int n = 0; n < 4; ++n) {
                const int gcol = v0 + wc * 64 + n * 16 + lo4;
                const float v  = acc[m][n][j];
                v_[n] = (gcol < V_DIM) ? v : -INFINITY;
                vmax = fmaxf(vmax, v_[n]);
            }
            #pragma unroll
            for (int d = 1; d < 16; d <<= 1)
                vmax = fmaxf(vmax, __shfl_xor(vmax, d, 64));
            float s = 0.f;
            if (vmax > -INFINITY) {         // uniform within 16-lane group
                #pragma unroll
                for (int n = 0; n < 4; ++n) s += __expf(v_[n] - vmax);
                #pragma unroll
                for (int d = 1; d < 16; d <<= 1)
                    s += __shfl_xor(s, d, 64);
            }
            if (lo4 == 0) {
                const int row = wr * 128 + m * 16 + hi2 * 4 + j;
                scrM[row * 4 + wc] = vmax;
                scrS[row * 4 + wc] = s;
            }
        }
    }
    __syncthreads();
    if (tid < 256) {
        float M = -INFINITY;
        #pragma unroll
        for (int w4 = 0; w4 < 4; ++w4) M = fmaxf(M, scrM[tid * 4 + w4]);
        float S = 0.f;
        #pragma unroll
        for (int w4 = 0; w4 < 4; ++w4) {
            const float mm = scrM[tid * 4 + w4];
            if (mm > -INFINITY) S += scrS[tid * 4 + w4] * __expf(mm - M);
        }
        const size_t idx = (size_t)vb * M_TOTAL + m0 + tid;
        pm[idx] = M;
        ps[idx] = S;
    }
}

// ---------------- picked logit: one wave per row ---------------------------
__global__ __launch_bounds__(256)
void lce_picked(const bf16_t* __restrict__ Xb, const bf16_t* __restrict__ Wb,
                const int* __restrict__ labels, float* __restrict__ picked)
{
    const int wv  = threadIdx.x >> 6, ln = threadIdx.x & 63;
    const int row = blockIdx.x * 4 + wv;
    const int lbl = labels[row];
    float s = 0.f;
    if (lbl != IGNORE_IDX) {
        const bf16_t* xr = Xb + (size_t)row * K_DIM;
        const bf16_t* wr = Wb + (size_t)lbl * K_DIM;
        #pragma unroll
        for (int c = 0; c < 4; ++c) {
            const bf16x8 a = *(const bf16x8*)(xr + c * 512 + ln * 8);
            const bf16x8 b = *(const bf16x8*)(wr + c * 512 + ln * 8);
            #pragma unroll
            for (int i = 0; i < 8; ++i) s += (float)a[i] * (float)b[i];
        }
    }
    #pragma unroll
    for (int d = 32; d; d >>= 1) s += __shfl_down(s, d, 64);
    if (ln == 0) picked[row] = s;
}

// ---------------- chunk-combine + finalize ---------------------------------
__global__ __launch_bounds__(256)
void lce_row_reduce(const float* __restrict__ pm, const float* __restrict__ ps,
                    const float* __restrict__ picked, const int* __restrict__ labels,
                    float* __restrict__ pb)
{
    const int r   = blockIdx.x * 256 + threadIdx.x;
    const int lbl = labels[r];
    float nll = 0.f, zsq = 0.f, val = 0.f;
    if (lbl != IGNORE_IDX) {
        float M = -INFINITY;
        for (int c = 0; c < NVB; ++c)
            M = fmaxf(M, pm[(size_t)c * M_TOTAL + r]);
        float S = 0.f;
        for (int c = 0; c < NVB; ++c) {
            const float mc = pm[(size_t)c * M_TOTAL + r];
            if (mc > -INFINITY) S += ps[(size_t)c * M_TOTAL + r] * expf(mc - M);
        }
        const float lse = M + logf(S);
        nll = lse - picked[r];
        zsq = lse * lse;
        val = 1.f;
    }
    #pragma unroll
    for (int d = 32; d; d >>= 1) {
        nll += __shfl_down(nll, d, 64);
        zsq += __shfl_down(zsq, d, 64);
        val += __shfl_down(val, d, 64);
    }
    __shared__ float red[3][4];
    const int wv = threadIdx.x >> 6, ln = threadIdx.x & 63;
    if (ln == 0) { red[0][wv] = nll; red[1][wv] = zsq; red[2][wv] = val; }
    __syncthreads();
    if (threadIdx.x == 0) {
        float a = 0.f, b = 0.f, c_ = 0.f;
        #pragma unroll
        for (int i = 0; i < 4; ++i) { a += red[0][i]; b += red[1][i]; c_ += red[2][i]; }
        pb[blockIdx.x * 3 + 0] = a;
        pb[blockIdx.x * 3 + 1] = b;
        pb[blockIdx.x * 3 + 2] = c_;
    }
}

__global__ void lce_finalize(const float* __restrict__ pb, float* __restrict__ out)
{
    float a = 0.f, b = 0.f, c_ = 0.f;
    for (int i = 0; i < 16; ++i) {
        a  += pb[i * 3 + 0];
        b  += pb[i * 3 + 1];
        c_ += pb[i * 3 + 2];
    }
    const float denom = fmaxf(c_, 1.f);
    float loss = a / denom;
    if (c_ > 0.f) loss += Z_REG * (b / denom);
    out[0] = loss;
}

// ---------------- fallback fused fp32 path (round-0 kernel, tiny ws) -------
#define FVC 1024
#define FNCHUNK 50
#define FBK 64
#define LDSPAD 72
__global__ __launch_bounds__(256)
void lce_gemm_stats_fused(const float* __restrict__ X, const float* __restrict__ W,
                          const int* __restrict__ labels,
                          float* __restrict__ pm, float* __restrict__ ps,
                          float* __restrict__ pp)
{
    __shared__ bf16_t As[128][LDSPAD];
    __shared__ bf16_t Bsh[128][LDSPAD];
    __shared__ float  sm[128], ss[128], sp[128];
    __shared__ float  part_m[2][128], part_s[2][128];
    __shared__ int    slab[128];

    const int bx    = blockIdx.x;
    const int chunk = bx >> 5;
    const int mb    = bx & 31;
    const int m0    = mb * 128;
    const int v0    = chunk * FVC;
    const int tid   = threadIdx.x;
    const int lane  = tid & 63;
    const int wave  = tid >> 6;
    const int wr    = wave >> 1;
    const int wc    = wave & 1;
    const int lo4   = lane & 15;
    const int hi2   = lane >> 4;
    const int sr0   = tid >> 4;
    const int sc4   = tid & 15;

    if (tid < 128) {
        sm[tid] = -INFINITY; ss[tid] = 0.f; sp[tid] = 0.f;
        slab[tid] = labels[m0 + tid];
    }
    __syncthreads();

    const int ncols = min(FVC, V_DIM - v0);
    const int nt    = (ncols + 127) >> 7;

    for (int vt = 0; vt < nt; ++vt) {
        f32x4 acc[4][4];
        #pragma unroll
        for (int m = 0; m < 4; ++m)
            #pragma unroll
            for (int n = 0; n < 4; ++n) {
                f32x4 z = {0.f, 0.f, 0.f, 0.f};
                acc[m][n] = z;
            }
        const int vrow0 = v0 + vt * 128;
        for (int kt = 0; kt < K_DIM / FBK; ++kt) {
            #pragma unroll
            for (int i = 0; i < 8; ++i) {
                const int row = i * 16 + sr0;
                const f32x4 va = *(const f32x4*)(X + (size_t)(m0 + row) * K_DIM + kt * FBK + sc4 * 4);
                *(bf16x4*)&As[row][sc4 * 4] = cvt4(va);
                const int grow = vrow0 + row;
                f32x4 vb = {0.f, 0.f, 0.f, 0.f};
                if (grow < V_DIM)
                    vb = *(const f32x4*)(W + (size_t)grow * K_DIM + kt * FBK + sc4 * 4);
                *(bf16x4*)&Bsh[row][sc4 * 4] = cvt4(vb);
            }
            __syncthreads();
            #pragma unroll
            for (int ks = 0; ks < 2; ++ks) {
                bf16x8 af[4], bfr[4];
                #pragma unroll
                for (int m = 0; m < 4; ++m)
                    af[m] = *(const bf16x8*)&As[wr * 64 + m * 16 + lo4][ks * 32 + hi2 * 8];
                #pragma unroll
                for (int n = 0; n < 4; ++n)
                    bfr[n] = *(const bf16x8*)&Bsh[wc * 64 + n * 16 + lo4][ks * 32 + hi2 * 8];
                #pragma unroll
                for (int m = 0; m < 4; ++m)
                    #pragma unroll
                    for (int n = 0; n < 4; ++n)
                        acc[m][n] = __builtin_amdgcn_mfma_f32_16x16x32_bf16(af[m], bfr[n], acc[m][n], 0, 0, 0);
            }
            __syncthreads();
        }
        const int vbase = vrow0 + wc * 64;
        #pragma unroll
        for (int m = 0; m < 4; ++m) {
            #pragma unroll
            for (int j = 0; j < 4; ++j) {
                const int rloc = wr * 64 + m * 16 + hi2 * 4 + j;
                const int lb   = slab[rloc];
                float vmax = -INFINITY;
                float v_[4];
                #pragma unroll
                for (int n = 0; n < 4; ++n) {
                    const int gcol = vbase + n * 16 + lo4;
                    const float v  = acc[m][n][j];
                    const bool ok  = (gcol < V_DIM);
                    v_[n] = ok ? v : -INFINITY;
                    if (ok && gcol == lb) sp[rloc] = v;
                    vmax = fmaxf(vmax, v_[n]);
                }
                #pragma unroll
                for (int d = 1; d < 16; d <<= 1)
                    vmax = fmaxf(vmax, __shfl_xor(vmax, d, 64));
                float s = 0.f;
                #pragma unroll
                for (int n = 0; n < 4; ++n) s += __expf(v_[n] - vmax);
                #pragma unroll
                for (int d = 1; d < 16; d <<= 1) s += __shfl_xor(s, d, 64);
                if (lo4 == 0) { part_m[wc][rloc] = vmax; part_s[wc][rloc] = s; }
            }
        }
        __syncthreads();
        if (tid < 128) {
            const float om  = sm[tid], os = ss[tid];
            const float m0_ = part_m[0][tid], s0 = part_s[0][tid];
            const float m1_ = part_m[1][tid], s1 = part_s[1][tid];
            const float nm  = fmaxf(om, fmaxf(m0_, m1_));
            float ns = 0.f;
            if (om  > -INFINITY) ns += os * __expf(om  - nm);
            if (m0_ > -INFINITY) ns += s0 * __expf(m0_ - nm);
            if (m1_ > -INFINITY) ns += s1 * __expf(m1_ - nm);
            sm[tid] = nm; ss[tid] = ns;
        }
    }
    __syncthreads();
    if (tid < 128) {
        const size_t idx = (size_t)chunk * M_TOTAL + (m0 + tid);
        pm[idx] = sm[tid]; ps[idx] = ss[tid]; pp[idx] = sp[tid];
    }
}

__global__ __launch_bounds__(256)
void lce_row_reduce_f(const float* __restrict__ pm, const float* __restrict__ ps,
                      const float* __restrict__ pp, const int* __restrict__ labels,
                      float* __restrict__ pb)
{
    const int r   = blockIdx.x * 256 + threadIdx.x;
    const int lbl = labels[r];
    float nll = 0.f, zsq = 0.f, val = 0.f;
    if (lbl != IGNORE_IDX) {
        float M = -INFINITY;
        for (int c = 0; c < FNCHUNK; ++c)
            M = fmaxf(M, pm[(size_t)c * M_TOTAL + r]);
        float S = 0.f, P = 0.f;
        for (int c = 0; c < FNCHUNK; ++c) {
            const float mc = pm[(size_t)c * M_TOTAL + r];
            if (mc > -INFINITY) S += ps[(size_t)c * M_TOTAL + r] * expf(mc - M);
            P += pp[(size_t)c * M_TOTAL + r];
        }
        const float lse = M + logf(S);
        nll = lse - P; zsq = lse * lse; val = 1.f;
    }
    #pragma unroll
    for (int d = 32; d; d >>= 1) {
        nll += __shfl_down(nll, d, 64);
        zsq += __shfl_down(zsq, d, 64);
        val += __shfl_down(val, d, 64);
    }
    __shared__ float red[3][4];
    const int wv = threadIdx.x >> 6, ln = threadIdx.x & 63;
    if (ln == 0) { red[0][wv] = nll; red[1][wv] = zsq; red[2][wv] = val; }
    __syncthreads();
    if (threadIdx.x == 0) {
        float a = 0.f, b = 0.f, c_ = 0.f;
        #pragma unroll
        for (int i = 0; i < 4; ++i) { a += red[0][i]; b += red[1][i]; c_ += red[2][i]; }
        pb[blockIdx.x * 3 + 0] = a;
        pb[blockIdx.x * 3 + 1] = b;
        pb[blockIdx.x * 3 + 2] = c_;
    }
}

extern "C" void kernel_launch(void* const* d_in, const int* in_sizes, int n_in,
                              void* d_out, int out_size, void* d_ws, size_t ws_size,
                              hipStream_t stream)
{
    const float* x      = (const float*)d_in[0];
    const int*   labels = (const int*)d_in[1];
    const float* w      = (const float*)d_in[2];
    float*       out    = (float*)d_out;

    const size_t wb_elems = (size_t)V_PAD * K_DIM;      // 103,284,736
    const size_t xb_elems = (size_t)M_TOTAL * K_DIM;    // 8,388,608
    const size_t stat_n   = (size_t)NVB * M_TOTAL;      // 806,912
    const size_t stat_off = wb_elems * 2 + xb_elems * 2;
    const size_t need     = stat_off + stat_n * 2 * sizeof(float)
                          + M_TOTAL * sizeof(float) + 16 * 3 * sizeof(float) + 256;

    if (ws_size >= need) {
        bf16_t* Wb     = (bf16_t*)d_ws;
        bf16_t* Xb     = Wb + wb_elems;
        float*  pm     = (float*)((char*)d_ws + stat_off);
        float*  ps     = pm + stat_n;
        float*  picked = ps + stat_n;
        float*  pb     = picked + M_TOTAL;

        cvt_f32_bf16<<<dim3(4096), dim3(256), 0, stream>>>(
            w, Wb, (long long)(wb_elems / 8), (long long)((size_t)V_DIM * K_DIM / 8));
        cvt_f32_bf16<<<dim3(1024), dim3(256), 0, stream>>>(
            x, Xb, (long long)(xb_elems / 8), (long long)(xb_elems / 8));
        lce_gemm8<<<dim3(NVB * 16), dim3(512), 0, stream>>>(Xb, Wb, pm, ps);
        lce_picked<<<dim3(1024), dim3(256), 0, stream>>>(Xb, Wb, labels, picked);
        lce_row_reduce<<<dim3(16), dim3(256), 0, stream>>>(pm, ps, picked, labels, pb);
        lce_finalize<<<dim3(1), dim3(1), 0, stream>>>(pb, out);
    } else {
        const size_t fstat_n = (size_t)FNCHUNK * M_TOTAL;
        float* pm = (float*)d_ws;
        float* ps = pm + fstat_n;
        float* pp = ps + fstat_n;
        float* pb = pp + fstat_n;
        lce_gemm_stats_fused<<<dim3(FNCHUNK * 32), dim3(256), 0, stream>>>(
            x, w, labels, pm, ps, pp);
        lce_row_reduce_f<<<dim3(16), dim3(256), 0, stream>>>(pm, ps, pp, labels, pb);
        lce_finalize<<<dim3(1), dim3(1), 0, stream>>>(pb, out);
    }
}